// Round 6
// baseline (469.795 us; speedup 1.0000x reference)
//
#include <hip/hip_runtime.h>
#include <math.h>

typedef unsigned short u16;
typedef unsigned int u32;

#define D_EMB 768
#define F_HID 3072
#define N_TOK 4096
#define N_PAIR 8192
#define GATE_TH 1e-9f

typedef float f32x4 __attribute__((ext_vector_type(4)));
typedef __bf16 bfrag __attribute__((ext_vector_type(8)));
typedef u16 u16x8 __attribute__((ext_vector_type(8)));

__device__ inline float b2f(u16 u) {
    union { float f; u32 i; } c; c.i = ((u32)u) << 16; return c.f;
}
__device__ inline u16 f2b(float f) {
    union { float f; u32 i; } c; c.f = f;
    u32 r = c.i + 0x7FFFu + ((c.i >> 16) & 1u);   // round-nearest-even
    return (u16)(r >> 16);
}
__device__ inline f32x4 mfma16(bfrag a, bfrag b, f32x4 c) {
    return __builtin_amdgcn_mfma_f32_16x16x32_bf16(a, b, c, 0, 0, 0);
}
// async global->LDS, 16B per lane. LDS dest = wave-uniform base + lane*16.
__device__ inline void gll16(const u16* g, u16* l) {
    __builtin_amdgcn_global_load_lds(
        (const __attribute__((address_space(1))) u32*)g,
        (__attribute__((address_space(3))) u32*)l, 16, 0, 0);
}
__device__ inline void sbar() {
    asm volatile("" ::: "memory");
    __builtin_amdgcn_s_barrier();
    asm volatile("" ::: "memory");
}
__device__ inline void waitv0() { asm volatile("s_waitcnt vmcnt(0)" ::: "memory"); }
__device__ inline void waitv4() { asm volatile("s_waitcnt vmcnt(4)" ::: "memory"); }

// ---------------------------------------------------------------- init / zero
__global__ void moe_init_kernel(int* __restrict__ cnt) {
    if (threadIdx.x < 8) cnt[threadIdx.x] = 0;
}
__global__ __launch_bounds__(256) void moe_zero_kernel(uint4* __restrict__ out) {
    int i = blockIdx.x * 256 + threadIdx.x;   // 786432 uint4 = 12.58 MB (fp32 out)
    out[i] = make_uint4(0, 0, 0, 0);
}

// ---------------------------------------------------------------- router v3 (fp32)
// 1 wave per block, 8 tokens: lane = (tl=lane&7 -> token, q=lane>>3 -> k-eighth).
// Also converts the block's 8 token rows to bf16 xb (fused, coalesced).
__global__ __launch_bounds__(64) void moe_router_v3(
    const float* __restrict__ x, const float* __restrict__ noise,
    const float* __restrict__ Wg, const float* __restrict__ bg,
    const float* __restrict__ Wn, const float* __restrict__ bn,
    int* __restrict__ tk_e, float* __restrict__ tk_g, int* __restrict__ cnt,
    ushort4* __restrict__ xb4)
{
    const int lane = threadIdx.x;
    const int tl = lane & 7, q = lane >> 3;
    const int t = blockIdx.x * 8 + tl;              // grid 512 -> 4096 tokens
    float ag[8] = {}, an[8] = {};
    const float4* xp = (const float4*)(x + (size_t)t * D_EMB + q * 96);
#pragma unroll 4
    for (int k4 = 0; k4 < 24; k4++) {
        float4 xv = xp[k4];
        const int kb = q * 96 + k4 * 4;
#pragma unroll
        for (int c = 0; c < 4; c++) {
            float xc = (&xv.x)[c];
            const float4* wg = (const float4*)(Wg + (size_t)(kb + c) * 8);
            const float4* wn = (const float4*)(Wn + (size_t)(kb + c) * 8);
            float4 g0 = wg[0], g1 = wg[1], n0 = wn[0], n1 = wn[1];
            ag[0] += xc * g0.x; ag[1] += xc * g0.y; ag[2] += xc * g0.z; ag[3] += xc * g0.w;
            ag[4] += xc * g1.x; ag[5] += xc * g1.y; ag[6] += xc * g1.z; ag[7] += xc * g1.w;
            an[0] += xc * n0.x; an[1] += xc * n0.y; an[2] += xc * n0.z; an[3] += xc * n0.w;
            an[4] += xc * n1.x; an[5] += xc * n1.y; an[6] += xc * n1.z; an[7] += xc * n1.w;
        }
    }
#pragma unroll
    for (int e = 0; e < 8; e++) {
        ag[e] += __shfl_xor(ag[e], 8);  an[e] += __shfl_xor(an[e], 8);
        ag[e] += __shfl_xor(ag[e], 16); an[e] += __shfl_xor(an[e], 16);
        ag[e] += __shfl_xor(ag[e], 32); an[e] += __shfl_xor(an[e], 32);
    }
    if (q == 0) {
        float best = -INFINITY, sec = -INFINITY; int be = 0, se = 0;
#pragma unroll
        for (int e = 0; e < 8; e++) {
            float nl = an[e] + bn[e];
            float sp = nl > 0.f ? nl + log1pf(expf(-nl)) : log1pf(expf(nl));  // softplus
            float v = ag[e] + bg[e] + noise[(size_t)t * 8 + e] * sp;
            if (v > best) { sec = best; se = be; best = v; be = e; }
            else if (v > sec) { sec = v; se = e; }
        }
        float ex = expf(sec - best);
        float g1 = 1.f / (1.f + ex), g2 = ex / (1.f + ex);
        tk_e[t * 2 + 0] = (g1 > GATE_TH) ? be : -1; tk_g[t * 2 + 0] = g1;
        tk_e[t * 2 + 1] = (g2 > GATE_TH) ? se : -1; tk_g[t * 2 + 1] = g2;
        if (g1 > GATE_TH) atomicAdd(&cnt[be], 1);
        if (g2 > GATE_TH) atomicAdd(&cnt[se], 1);
    }
    // fused x -> bf16 (coalesced): 8 tokens * 192 ushort4
    if (xb4) {
        const int t0 = blockIdx.x * 8;
        for (int i = lane; i < 8 * 192; i += 64) {
            int ti = i / 192, c = i - ti * 192;
            float4 v = *(const float4*)(x + (size_t)(t0 + ti) * D_EMB + c * 4);
            ushort4 o;
            o.x = f2b(v.x); o.y = f2b(v.y); o.z = f2b(v.z); o.w = f2b(v.w);
            xb4[(size_t)(t0 + ti) * 192 + c] = o;
        }
    }
}

// ---------------------------------------------------------------- offsets / scatter
__global__ void moe_offsets_kernel(const int* __restrict__ cnt,
                                   int* __restrict__ off, int* __restrict__ cursor) {
    if (threadIdx.x == 0) {
        int s = 0;
        for (int e = 0; e < 8; e++) { off[e] = s; cursor[e] = s; s += cnt[e]; }
    }
}
__global__ void moe_scatter_kernel(const int* __restrict__ tk_e, const float* __restrict__ tk_g,
                                   int* __restrict__ cursor, int* __restrict__ plist,
                                   float* __restrict__ pg, int* __restrict__ pos) {
    int i = blockIdx.x * 256 + threadIdx.x;
    if (i < N_PAIR) {
        int e = tk_e[i];
        if (e >= 0) {
            int p = atomicAdd(&cursor[e], 1);
            plist[p] = i >> 1;
            pg[p] = tk_g[i];
            pos[i] = p;
        }
    }
}

// ---------------------------------------------------------------- transpose+convert v2
// in fp32 [Z][R][C] -> out bf16 [Z][C][R]. 128(R) x 32(C) tile per block.
// float4 reads, ushort8 (16B) writes, pad-33 LDS (bank = (r+c)%32, conflict-free).
__global__ __launch_bounds__(256) void moe_transcvt_kernel(
    const float* __restrict__ in, u16* __restrict__ out, int R, int C) {
    __shared__ float tile[128][33];
    const int z = blockIdx.z;
    const int c0 = blockIdx.x * 32, r0 = blockIdx.y * 128;
    const size_t base = (size_t)z * R * C;
    const int t = threadIdx.x;
    {
        const int row = t >> 1, cb = (t & 1) * 16;
        const float* src = in + base + (size_t)(r0 + row) * C + c0 + cb;
        float4 v0 = *(const float4*)(src + 0);
        float4 v1 = *(const float4*)(src + 4);
        float4 v2 = *(const float4*)(src + 8);
        float4 v3 = *(const float4*)(src + 12);
        float* d = &tile[row][cb];
        d[0]  = v0.x; d[1]  = v0.y; d[2]  = v0.z; d[3]  = v0.w;
        d[4]  = v1.x; d[5]  = v1.y; d[6]  = v1.z; d[7]  = v1.w;
        d[8]  = v2.x; d[9]  = v2.y; d[10] = v2.z; d[11] = v2.w;
        d[12] = v3.x; d[13] = v3.y; d[14] = v3.z; d[15] = v3.w;
    }
    __syncthreads();
    const int c = t >> 3, ua = t & 7;
#pragma unroll
    for (int k = 0; k < 2; k++) {
        int rr = (ua + k * 8) * 8;
        u16x8 o;
#pragma unroll
        for (int i = 0; i < 8; i++) o[i] = f2b(tile[rr + i][c]);
        *(u16x8*)(out + base + (size_t)(c0 + c) * R + r0 + rr) = o;
    }
}

// ---------------------------------------------------------------- FFN1 GEMM
// h[p-P0] = relu(xb[plist[p]] . wt[e]^T + b1[e])
// 128x128 tile, BK=32, dbuf LDS (32 KB total -> ~3 blocks/CU), global_load_lds
// staging with r1-proven source-side XOR slot swizzle, counted vmcnt(4)
// prefetch (next tile's 4 loads in flight across compute). XCD-chunked swizzle.
__global__ __launch_bounds__(256) void moe_ffn1_kernel(
    const u16* __restrict__ xb, const u16* __restrict__ wt, const float* __restrict__ b1,
    const int* __restrict__ plist, const int* __restrict__ cnt, const int* __restrict__ off,
    u16* __restrict__ h, int P0, int P1)
{
    __shared__ __align__(16) u16 As[2][128 * 32];   // 2 x 8 KB
    __shared__ __align__(16) u16 Bs[2][128 * 32];   // 2 x 8 KB
    const int GX = 24, GY = 16;                     // grid = (24,16,8), nwg=3072
    int f = blockIdx.x + GX * (blockIdx.y + GY * blockIdx.z);
    int swz = (f & 7) * 384 + (f >> 3);             // bijective, chunk=384=one expert
    int nb = swz % GX;
    int t2 = swz / GX;
    int mb = t2 % GY;
    int e  = t2 / GY;

    int lo = off[e], hi = lo + cnt[e];
    if (lo < P0) lo = P0;
    if (hi > P1) hi = P1;
    const int Cl = hi - lo;
    if (Cl <= 0) return;
    const int n0 = nb * 128;
    const int tid = threadIdx.x;
    const int lane = tid & 63, wave = tid >> 6;
    const int wr = wave >> 1, wc = wave & 1;
    const int qq = lane >> 4, r = lane & 15;
    const int qa = (qq ^ ((r >> 1) & 3)) * 8;       // swizzled read slot (u16)
    const int srow = tid >> 2;                      // 0..63 (row within 64-row round)
    const int gq = (tid & 3) ^ ((tid >> 3) & 3);    // swizzled source 16B-slot

    const u16* bsrc0 = wt + ((size_t)e * F_HID + n0 + srow) * D_EMB + gq * 8;
    const u16* bsrc1 = bsrc0 + (size_t)64 * D_EMB;

    for (int m0 = mb * 128; m0 < Cl; m0 += GY * 128) {
        int mr0 = m0 + srow;      if (mr0 > Cl - 1) mr0 = Cl - 1;
        int mr1 = m0 + 64 + srow; if (mr1 > Cl - 1) mr1 = Cl - 1;
        const u16* asrc0 = xb + (size_t)plist[lo + mr0] * D_EMB + gq * 8;
        const u16* asrc1 = xb + (size_t)plist[lo + mr1] * D_EMB + gq * 8;
        f32x4 acc[4][4] = {};

        auto stage = [&](int kt, int buf) {
            const int k0 = kt * 32;
            gll16(asrc0 + k0, &As[buf][wave * 512]);
            gll16(asrc1 + k0, &As[buf][2048 + wave * 512]);
            gll16(bsrc0 + k0, &Bs[buf][wave * 512]);
            gll16(bsrc1 + k0, &Bs[buf][2048 + wave * 512]);
        };
        auto compute = [&](int buf) {
            bfrag af[4], bf[4];
#pragma unroll
            for (int i = 0; i < 4; i++) {
                af[i] = *(const bfrag*)(&As[buf][(wr * 64 + i * 16 + r) * 32 + qa]);
                bf[i] = *(const bfrag*)(&Bs[buf][(wc * 64 + i * 16 + r) * 32 + qa]);
            }
#pragma unroll
            for (int mi = 0; mi < 4; mi++)
#pragma unroll
                for (int ni = 0; ni < 4; ni++)
                    acc[mi][ni] = mfma16(af[mi], bf[ni], acc[mi][ni]);
        };

        waitv0();                        // drain prior epilogue stores
        stage(0, 0);
        for (int kt = 0; kt < 23; kt++) {   // NT = 768/32 = 24
            stage(kt + 1, (kt + 1) & 1);
            waitv4(); sbar();            // tile kt landed; kt+1 in flight
            compute(kt & 1);
            sbar();
        }
        waitv0(); sbar();
        compute(1);                      // kt = 23

#pragma unroll
        for (int mi = 0; mi < 4; mi++)
#pragma unroll
            for (int ni = 0; ni < 4; ni++) {
                int col = n0 + wc * 64 + ni * 16 + r;
                float bias = b1[(size_t)e * F_HID + col];
#pragma unroll
                for (int i = 0; i < 4; i++) {
                    int m = m0 + wr * 64 + mi * 16 + qq * 4 + i;
                    if (m < Cl) {
                        float v = acc[mi][ni][i] + bias;
                        h[(size_t)(lo - P0 + m) * F_HID + col] = f2b(v > 0.f ? v : 0.f);
                    }
                }
            }
        sbar();                          // protect buffers from next m-iter staging
    }
}

// ---------------------------------------------------------------- FFN2 GEMM
// y[p] = h[p-P0] . wt[e]^T + b2[e]  (plain stores, no atomics)
// Same 128x128 / BK=32 / dbuf / vmcnt(4) structure as ffn1; A from h.
__global__ __launch_bounds__(256) void moe_ffn2_kernel(
    const u16* __restrict__ h, const u16* __restrict__ wt, const float* __restrict__ b2,
    const int* __restrict__ cnt, const int* __restrict__ off,
    float* __restrict__ y, int P0, int P1)
{
    __shared__ __align__(16) u16 As[2][128 * 32];   // 2 x 8 KB
    __shared__ __align__(16) u16 Bs[2][128 * 32];   // 2 x 8 KB
    const int GX = 6, GY = 16;                      // grid = (6,16,8), nwg=768
    int f = blockIdx.x + GX * (blockIdx.y + GY * blockIdx.z);
    int swz = (f & 7) * 96 + (f >> 3);              // chunk=96=one expert
    int nb = swz % GX;
    int t2 = swz / GX;
    int mb = t2 % GY;
    int e  = t2 / GY;

    int lo = off[e], hi = lo + cnt[e];
    if (lo < P0) lo = P0;
    if (hi > P1) hi = P1;
    const int Cl = hi - lo;
    if (Cl <= 0) return;
    const int n0 = nb * 128;
    const int tid = threadIdx.x;
    const int lane = tid & 63, wave = tid >> 6;
    const int wr = wave >> 1, wc = wave & 1;
    const int qq = lane >> 4, r = lane & 15;
    const int qa = (qq ^ ((r >> 1) & 3)) * 8;
    const int srow = tid >> 2;
    const int gq = (tid & 3) ^ ((tid >> 3) & 3);
    const int hcap = P1 - P0;

    const u16* bsrc0 = wt + ((size_t)e * D_EMB + n0 + srow) * F_HID + gq * 8;
    const u16* bsrc1 = bsrc0 + (size_t)64 * F_HID;

    for (int m0 = mb * 128; m0 < Cl; m0 += GY * 128) {
        int mr0 = m0 + srow;      if (mr0 > Cl - 1) mr0 = Cl - 1;
        int mr1 = m0 + 64 + srow; if (mr1 > Cl - 1) mr1 = Cl - 1;
        if (mr0 >= hcap) mr0 = hcap - 1;
        if (mr1 >= hcap) mr1 = hcap - 1;
        const u16* asrc0 = h + (size_t)(lo - P0 + mr0) * F_HID + gq * 8;
        const u16* asrc1 = h + (size_t)(lo - P0 + mr1) * F_HID + gq * 8;
        f32x4 acc[4][4] = {};

        auto stage = [&](int kt, int buf) {
            const int k0 = kt * 32;
            gll16(asrc0 + k0, &As[buf][wave * 512]);
            gll16(asrc1 + k0, &As[buf][2048 + wave * 512]);
            gll16(bsrc0 + k0, &Bs[buf][wave * 512]);
            gll16(bsrc1 + k0, &Bs[buf][2048 + wave * 512]);
        };
        auto compute = [&](int buf) {
            bfrag af[4], bf[4];
#pragma unroll
            for (int i = 0; i < 4; i++) {
                af[i] = *(const bfrag*)(&As[buf][(wr * 64 + i * 16 + r) * 32 + qa]);
                bf[i] = *(const bfrag*)(&Bs[buf][(wc * 64 + i * 16 + r) * 32 + qa]);
            }
#pragma unroll
            for (int mi = 0; mi < 4; mi++)
#pragma unroll
                for (int ni = 0; ni < 4; ni++)
                    acc[mi][ni] = mfma16(af[mi], bf[ni], acc[mi][ni]);
        };

        waitv0();
        stage(0, 0);
        for (int kt = 0; kt < 95; kt++) {   // NT = 3072/32 = 96
            stage(kt + 1, (kt + 1) & 1);
            waitv4(); sbar();
            compute(kt & 1);
            sbar();
        }
        waitv0(); sbar();
        compute(1);                      // kt = 95

#pragma unroll
        for (int mi = 0; mi < 4; mi++)
#pragma unroll
            for (int ni = 0; ni < 4; ni++) {
                int col = n0 + wc * 64 + ni * 16 + r;
                float bias = b2[(size_t)e * D_EMB + col];
#pragma unroll
                for (int i = 0; i < 4; i++) {
                    int m = m0 + wr * 64 + mi * 16 + qq * 4 + i;
                    if (m < Cl)
                        y[(size_t)(lo + m) * D_EMB + col] = acc[mi][ni][i] + bias;
                }
            }
        sbar();
    }
}

// ---------------------------------------------------------------- combine
// out[t] = sum_k gate[t,k] * y[pos[t,k]]  (writes every token -> no zero pass)
__global__ __launch_bounds__(256) void moe_combine_kernel(
    const float* __restrict__ y, const int* __restrict__ tk_e,
    const float* __restrict__ tk_g, const int* __restrict__ pos,
    float4* __restrict__ out)
{
    int i = blockIdx.x * 256 + threadIdx.x;   // 786432 float4
    int t = i / 192;
    int c = i - t * 192;
    float4 a = make_float4(0.f, 0.f, 0.f, 0.f);
#pragma unroll
    for (int k = 0; k < 2; k++) {
        int e = tk_e[t * 2 + k];
        if (e >= 0) {
            float g = tk_g[t * 2 + k];
            float4 v = ((const float4*)(y + (size_t)pos[t * 2 + k] * D_EMB))[c];
            a.x += g * v.x; a.y += g * v.y; a.z += g * v.z; a.w += g * v.w;
        }
    }
    out[i] = a;
}

// ---------------------------------------------------------------- fallback fused FFN (fp32)
#define XSTR 776
#define HSTR 3080
#define BMF 8
__global__ __launch_bounds__(256) void moe_ffn_fused_f32(
    const float* __restrict__ x,
    const float* __restrict__ w1, const float* __restrict__ b1,
    const float* __restrict__ w2, const float* __restrict__ b2,
    const int* __restrict__ plist, const float* __restrict__ pg,
    const int* __restrict__ cnt, const int* __restrict__ off,
    float* __restrict__ out)
{
    __shared__ __align__(16) u16 xs[BMF * XSTR];
    __shared__ __align__(16) u16 hs[BMF * HSTR];
    const int e = blockIdx.x;
    const int Cl = cnt[e];
    if (Cl <= 0) return;
    const int O = off[e];
    const int tid = threadIdx.x;
    for (int t0 = blockIdx.y * BMF; t0 < Cl; t0 += gridDim.y * BMF) {
        for (int ci = tid; ci < BMF * 192; ci += 256) {
            int row = ci / 192, c = ci - row * 192;
            float4 v = make_float4(0.f, 0.f, 0.f, 0.f);
            if (t0 + row < Cl) {
                int tok = plist[O + t0 + row];
                v = *(const float4*)(x + (size_t)tok * D_EMB + c * 4);
            }
            u16* d = &xs[row * XSTR + c * 4];
            d[0] = f2b(v.x); d[1] = f2b(v.y); d[2] = f2b(v.z); d[3] = f2b(v.w);
        }
        __syncthreads();
        for (int wi = tid; wi < BMF * 768; wi += 256) {
            int row = wi / 768, nc = wi - row * 768;
            int n0 = nc * 4;
            float a0 = 0, a1 = 0, a2 = 0, a3 = 0;
            const float* wp = w1 + (size_t)e * D_EMB * F_HID + n0;
            const u16* xr = &xs[row * XSTR];
            for (int k = 0; k < D_EMB; k++) {
                float4 wv = *(const float4*)(wp + (size_t)k * F_HID);
                float xv = b2f(xr[k]);
                a0 += xv * wv.x; a1 += xv * wv.y; a2 += xv * wv.z; a3 += xv * wv.w;
            }
            const float* bp = b1 + (size_t)e * F_HID + n0;
            u16* hp = &hs[row * HSTR + n0];
            float v;
            v = a0 + bp[0]; hp[0] = f2b(v > 0.f ? v : 0.f);
            v = a1 + bp[1]; hp[1] = f2b(v > 0.f ? v : 0.f);
            v = a2 + bp[2]; hp[2] = f2b(v > 0.f ? v : 0.f);
            v = a3 + bp[3]; hp[3] = f2b(v > 0.f ? v : 0.f);
        }
        __syncthreads();
        for (int wi = tid; wi < BMF * 192; wi += 256) {
            int row = wi / 192, nc = wi - row * 192;
            int n0 = nc * 4;
            float a0 = 0, a1 = 0, a2 = 0, a3 = 0;
            const float* wp = w2 + (size_t)e * F_HID * D_EMB + n0;
            const u16* hr = &hs[row * HSTR];
            for (int k = 0; k < F_HID; k++) {
                float4 wv = *(const float4*)(wp + (size_t)k * D_EMB);
                float hv = b2f(hr[k]);
                a0 += hv * wv.x; a1 += hv * wv.y; a2 += hv * wv.z; a3 += hv * wv.w;
            }
            if (t0 + row < Cl) {
                int p = O + t0 + row;
                int tok = plist[p];
                float g = pg[p];
                const float* bp = b2 + (size_t)e * D_EMB + n0;
                float* op = out + (size_t)tok * D_EMB + n0;
                atomicAdd(&op[0], g * (a0 + bp[0]));
                atomicAdd(&op[1], g * (a1 + bp[1]));
                atomicAdd(&op[2], g * (a2 + bp[2]));
                atomicAdd(&op[3], g * (a3 + bp[3]));
            }
        }
        __syncthreads();
    }
}

// ---------------------------------------------------------------- launch
extern "C" void kernel_launch(void* const* d_in, const int* in_sizes, int n_in,
                              void* d_out, int out_size, void* d_ws, size_t ws_size,
                              hipStream_t stream) {
    const float* x     = (const float*)d_in[0];
    const float* noise = (const float*)d_in[1];
    const float* Wg    = (const float*)d_in[2];
    const float* bg    = (const float*)d_in[3];
    const float* Wn    = (const float*)d_in[4];
    const float* bn    = (const float*)d_in[5];
    const float* W1    = (const float*)d_in[6];
    const float* b1    = (const float*)d_in[7];
    const float* W2    = (const float*)d_in[8];
    const float* b2    = (const float*)d_in[9];
    float* out = (float*)d_out;

    // workspace layout (shared small region)
    char* ws = (char*)d_ws;
    int*   cnt    = (int*)(ws + 0);
    int*   off    = (int*)(ws + 256);
    int*   cursor = (int*)(ws + 512);
    int*   tk_e   = (int*)(ws + 1024);       // 32768 B
    float* tk_g   = (float*)(ws + 33792);    // 32768 B
    int*   plist  = (int*)(ws + 66560);      // 32768 B
    float* pg     = (float*)(ws + 99328);    // 32768 B
    int*   pos    = (int*)(ws + 132096);     // 32768 B
    const size_t SMALL  = 164864;
    const size_t WSZ    = 37748736ull;       // one transposed weight set (bf16)
    const size_t XB_SZ  = 6291456ull;        // 4096*768*2
    const size_t Y_SZ   = 25165824ull;       // 8192*768*4
    const size_t H_FULL = 50331648ull;       // 8192*3072*2

    // Plan A: single-pass, ONE shared weight buffer (transcvt W1 -> ffn1 ->
    // transcvt W2 -> ffn2). NEED_A = 119.7 MB (< known-good 126 MB floor).
    const size_t NEED_A = SMALL + WSZ + XB_SZ + Y_SZ + H_FULL;

    if (ws_size >= NEED_A) {
        u16*   wt = (u16*)(ws + SMALL);
        u16*   xb = (u16*)(ws + SMALL + WSZ);
        float* y  = (float*)(ws + SMALL + WSZ + XB_SZ);
        u16*   h  = (u16*)(ws + SMALL + WSZ + XB_SZ + Y_SZ);

        moe_init_kernel<<<dim3(1), dim3(64), 0, stream>>>(cnt);
        moe_router_v3<<<dim3(512), dim3(64), 0, stream>>>(
            x, noise, Wg, bg, Wn, bn, tk_e, tk_g, cnt, (ushort4*)xb);
        moe_offsets_kernel<<<dim3(1), dim3(64), 0, stream>>>(cnt, off, cursor);
        moe_scatter_kernel<<<dim3(N_PAIR / 256), dim3(256), 0, stream>>>(
            tk_e, tk_g, cursor, plist, pg, pos);
        moe_transcvt_kernel<<<dim3(F_HID / 32, D_EMB / 128, 8), dim3(256), 0, stream>>>(
            W1, wt, D_EMB, F_HID);   // [e][768][3072] -> [e][3072][768]
        moe_ffn1_kernel<<<dim3(24, 16, 8), dim3(256), 0, stream>>>(
            xb, wt, b1, plist, cnt, off, h, 0, N_PAIR);
        moe_transcvt_kernel<<<dim3(D_EMB / 32, F_HID / 128, 8), dim3(256), 0, stream>>>(
            W2, wt, F_HID, D_EMB);   // [e][3072][768] -> [e][768][3072]
        moe_ffn2_kernel<<<dim3(6, 16, 8), dim3(256), 0, stream>>>(
            h, wt, b2, cnt, off, y, 0, N_PAIR);
        moe_combine_kernel<<<dim3(3072), dim3(256), 0, stream>>>(
            y, tk_e, tk_g, pos, (float4*)out);
        (void)in_sizes; (void)n_in; (void)out_size;
        return;
    }

    // Plan B: chunked, separate w1t/w2t buffers.
    const size_t B_BASE = SMALL + 2 * WSZ + XB_SZ + Y_SZ;
    int pchunk = 0;
    for (int p = N_PAIR; p >= 512; p >>= 1) {
        if (B_BASE + (size_t)p * F_HID * 2 <= ws_size) { pchunk = p; break; }
    }

    moe_init_kernel<<<dim3(1), dim3(64), 0, stream>>>(cnt);
    moe_router_v3<<<dim3(512), dim3(64), 0, stream>>>(
        x, noise, Wg, bg, Wn, bn, tk_e, tk_g, cnt,
        pchunk > 0 ? (ushort4*)(ws + SMALL + 2 * WSZ) : (ushort4*)0);
    moe_offsets_kernel<<<dim3(1), dim3(64), 0, stream>>>(cnt, off, cursor);
    moe_scatter_kernel<<<dim3(N_PAIR / 256), dim3(256), 0, stream>>>(
        tk_e, tk_g, cursor, plist, pg, pos);

    if (pchunk > 0) {
        u16*   w1t = (u16*)(ws + SMALL);
        u16*   w2t = (u16*)(ws + SMALL + WSZ);
        u16*   xb  = (u16*)(ws + SMALL + 2 * WSZ);
        float* y   = (float*)(ws + SMALL + 2 * WSZ + XB_SZ);
        u16*   h   = (u16*)(ws + B_BASE);
        moe_transcvt_kernel<<<dim3(F_HID / 32, D_EMB / 128, 8), dim3(256), 0, stream>>>(
            W1, w1t, D_EMB, F_HID);
        moe_transcvt_kernel<<<dim3(D_EMB / 32, F_HID / 128, 8), dim3(256), 0, stream>>>(
            W2, w2t, F_HID, D_EMB);
        for (int c = 0; c < N_PAIR / pchunk; c++) {
            int P0 = c * pchunk, P1 = P0 + pchunk;
            moe_ffn1_kernel<<<dim3(24, 16, 8), dim3(256), 0, stream>>>(
                xb, w1t, b1, plist, cnt, off, h, P0, P1);
            moe_ffn2_kernel<<<dim3(6, 16, 8), dim3(256), 0, stream>>>(
                h, w2t, b2, cnt, off, y, P0, P1);
        }
        moe_combine_kernel<<<dim3(3072), dim3(256), 0, stream>>>(
            y, tk_e, tk_g, pos, (float4*)out);
    } else {
        moe_zero_kernel<<<dim3(3072), dim3(256), 0, stream>>>((uint4*)out);
        moe_ffn_fused_f32<<<dim3(8, 192), dim3(256), 0, stream>>>(
            x, W1, b1, W2, b2, plist, pg, cnt, off, out);
    }
    (void)in_sizes; (void)n_in; (void)out_size;
}

// Round 7
// 413.985 us; speedup vs baseline: 1.1348x; 1.1348x over previous
//
#include <hip/hip_runtime.h>
#include <math.h>

typedef unsigned short u16;
typedef unsigned int u32;

#define D_EMB 768
#define F_HID 3072
#define N_TOK 4096
#define N_PAIR 8192
#define GATE_TH 1e-9f

typedef float f32x4 __attribute__((ext_vector_type(4)));
typedef __bf16 bfrag __attribute__((ext_vector_type(8)));
typedef u16 u16x8 __attribute__((ext_vector_type(8)));

__device__ inline float b2f(u16 u) {
    union { float f; u32 i; } c; c.i = ((u32)u) << 16; return c.f;
}
__device__ inline u16 f2b(float f) {
    union { float f; u32 i; } c; c.f = f;
    u32 r = c.i + 0x7FFFu + ((c.i >> 16) & 1u);   // round-nearest-even
    return (u16)(r >> 16);
}
__device__ inline f32x4 mfma16(bfrag a, bfrag b, f32x4 c) {
    return __builtin_amdgcn_mfma_f32_16x16x32_bf16(a, b, c, 0, 0, 0);
}
// async global->LDS, 16B per lane. LDS dest = wave-uniform base + lane*16.
__device__ inline void gll16(const u16* g, u16* l) {
    __builtin_amdgcn_global_load_lds(
        (const __attribute__((address_space(1))) u32*)g,
        (__attribute__((address_space(3))) u32*)l, 16, 0, 0);
}
__device__ inline void sbar() {
    asm volatile("" ::: "memory");
    __builtin_amdgcn_s_barrier();
    asm volatile("" ::: "memory");
}
__device__ inline void waitv0() { asm volatile("s_waitcnt vmcnt(0)" ::: "memory"); }
__device__ inline void waitv6() { asm volatile("s_waitcnt vmcnt(6)" ::: "memory"); }
__device__ inline void waitv8() { asm volatile("s_waitcnt vmcnt(8)" ::: "memory"); }

// ---------------------------------------------------------------- zero (fallback only)
__global__ __launch_bounds__(256) void moe_zero_kernel(uint4* __restrict__ out) {
    int i = blockIdx.x * 256 + threadIdx.x;   // 786432 uint4 = 12.58 MB (fp32 out)
    out[i] = make_uint4(0, 0, 0, 0);
}

// ---------------------------------------------------------------- router v4 (fp32)
// 1 wave per block, 8 tokens: lane = (tl=lane&7 -> token, q=lane>>3 -> k-eighth).
// No atomics (plan kernel counts). Also converts the block's 8 token rows to bf16.
__global__ __launch_bounds__(64) void moe_router_v4(
    const float* __restrict__ x, const float* __restrict__ noise,
    const float* __restrict__ Wg, const float* __restrict__ bg,
    const float* __restrict__ Wn, const float* __restrict__ bn,
    int* __restrict__ tk_e, float* __restrict__ tk_g,
    ushort4* __restrict__ xb4)
{
    const int lane = threadIdx.x;
    const int tl = lane & 7, q = lane >> 3;
    const int t = blockIdx.x * 8 + tl;              // grid 512 -> 4096 tokens
    float ag[8] = {}, an[8] = {};
    const float4* xp = (const float4*)(x + (size_t)t * D_EMB + q * 96);
#pragma unroll 4
    for (int k4 = 0; k4 < 24; k4++) {
        float4 xv = xp[k4];
        const int kb = q * 96 + k4 * 4;
#pragma unroll
        for (int c = 0; c < 4; c++) {
            float xc = (&xv.x)[c];
            const float4* wg = (const float4*)(Wg + (size_t)(kb + c) * 8);
            const float4* wn = (const float4*)(Wn + (size_t)(kb + c) * 8);
            float4 g0 = wg[0], g1 = wg[1], n0 = wn[0], n1 = wn[1];
            ag[0] += xc * g0.x; ag[1] += xc * g0.y; ag[2] += xc * g0.z; ag[3] += xc * g0.w;
            ag[4] += xc * g1.x; ag[5] += xc * g1.y; ag[6] += xc * g1.z; ag[7] += xc * g1.w;
            an[0] += xc * n0.x; an[1] += xc * n0.y; an[2] += xc * n0.z; an[3] += xc * n0.w;
            an[4] += xc * n1.x; an[5] += xc * n1.y; an[6] += xc * n1.z; an[7] += xc * n1.w;
        }
    }
#pragma unroll
    for (int e = 0; e < 8; e++) {
        ag[e] += __shfl_xor(ag[e], 8);  an[e] += __shfl_xor(an[e], 8);
        ag[e] += __shfl_xor(ag[e], 16); an[e] += __shfl_xor(an[e], 16);
        ag[e] += __shfl_xor(ag[e], 32); an[e] += __shfl_xor(an[e], 32);
    }
    if (q == 0) {
        float best = -INFINITY, sec = -INFINITY; int be = 0, se = 0;
#pragma unroll
        for (int e = 0; e < 8; e++) {
            float nl = an[e] + bn[e];
            float sp = nl > 0.f ? nl + log1pf(expf(-nl)) : log1pf(expf(nl));  // softplus
            float v = ag[e] + bg[e] + noise[(size_t)t * 8 + e] * sp;
            if (v > best) { sec = best; se = be; best = v; be = e; }
            else if (v > sec) { sec = v; se = e; }
        }
        float ex = expf(sec - best);
        float g1 = 1.f / (1.f + ex), g2 = ex / (1.f + ex);
        tk_e[t * 2 + 0] = (g1 > GATE_TH) ? be : -1; tk_g[t * 2 + 0] = g1;
        tk_e[t * 2 + 1] = (g2 > GATE_TH) ? se : -1; tk_g[t * 2 + 1] = g2;
    }
    // fused x -> bf16 (coalesced): 8 tokens * 192 ushort4
    if (xb4) {
        const int t0 = blockIdx.x * 8;
        for (int i = lane; i < 8 * 192; i += 64) {
            int ti = i / 192, c = i - ti * 192;
            float4 v = *(const float4*)(x + (size_t)(t0 + ti) * D_EMB + c * 4);
            ushort4 o;
            o.x = f2b(v.x); o.y = f2b(v.y); o.z = f2b(v.z); o.w = f2b(v.w);
            xb4[(size_t)(t0 + ti) * 192 + c] = o;
        }
    }
}

// ---------------------------------------------------------------- plan (count+scan+scatter)
// Single block, 256 threads, no global atomics. Deterministic placement.
__global__ __launch_bounds__(256) void moe_plan_kernel(
    const int* __restrict__ tk_e, const float* __restrict__ tk_g,
    int* __restrict__ cnt, int* __restrict__ off,
    int* __restrict__ plist, float* __restrict__ pg, int* __restrict__ pos)
{
    __shared__ int lc[8 * 256];    // per-(expert, thread) counters; bank = t%32
    __shared__ int ob[8];
    const int t = threadIdx.x;
#pragma unroll
    for (int e = 0; e < 8; e++) lc[e * 256 + t] = 0;
    __syncthreads();
    const int i0 = t * 32;         // 32 pairs per thread
    for (int j = 0; j < 32; j++) {
        int e = tk_e[i0 + j];
        if (e >= 0) lc[e * 256 + t]++;
    }
    __syncthreads();
    if (t < 8) {                   // exclusive scan over 256 thread-counts per expert
        int s = 0;
        for (int u = 0; u < 256; u++) {
            int v = lc[t * 256 + u]; lc[t * 256 + u] = s; s += v;
        }
        ob[t] = s;                 // expert total
    }
    __syncthreads();
    if (t == 0) {
        int s = 0;
        for (int e = 0; e < 8; e++) {
            int v = ob[e]; cnt[e] = v; off[e] = s; ob[e] = s; s += v;
        }
    }
    __syncthreads();
    for (int j = 0; j < 32; j++) {
        int e = tk_e[i0 + j];
        if (e >= 0) {
            int p = ob[e] + lc[e * 256 + t]++;
            plist[p] = (i0 + j) >> 1;
            pg[p] = tk_g[i0 + j];
            pos[i0 + j] = p;
        }
    }
}

// ---------------------------------------------------------------- transpose+convert v3
// in fp32 [Z][R][C] -> out bf16 [Z][C][R]. 64x64 tile: 256B-chunk reads,
// 128B-chunk writes, pad-65 fp32 LDS (<=2-way bank alias, free).
__global__ __launch_bounds__(256) void moe_transcvt_kernel(
    const float* __restrict__ in, u16* __restrict__ out, int R, int C) {
    __shared__ float tile[64][65];
    const int z = blockIdx.z;
    const int c0 = blockIdx.x * 64, r0 = blockIdx.y * 64;
    const size_t base = (size_t)z * R * C;
    const int t = threadIdx.x;
    {
        const int row = t >> 2, cb = (t & 3) * 16;
        const float* src = in + base + (size_t)(r0 + row) * C + c0 + cb;
        float4 v0 = ((const float4*)src)[0];
        float4 v1 = ((const float4*)src)[1];
        float4 v2 = ((const float4*)src)[2];
        float4 v3 = ((const float4*)src)[3];
        float* d = &tile[row][cb];
        d[0]  = v0.x; d[1]  = v0.y; d[2]  = v0.z; d[3]  = v0.w;
        d[4]  = v1.x; d[5]  = v1.y; d[6]  = v1.z; d[7]  = v1.w;
        d[8]  = v2.x; d[9]  = v2.y; d[10] = v2.z; d[11] = v2.w;
        d[12] = v3.x; d[13] = v3.y; d[14] = v3.z; d[15] = v3.w;
    }
    __syncthreads();
    const int c = t >> 2, rb = (t & 3) * 16;
    u16x8 o0, o1;
#pragma unroll
    for (int i = 0; i < 8; i++) o0[i] = f2b(tile[rb + i][c]);
#pragma unroll
    for (int i = 0; i < 8; i++) o1[i] = f2b(tile[rb + 8 + i][c]);
    u16* dst = out + base + (size_t)(c0 + c) * R + r0 + rb;
    *(u16x8*)dst = o0;
    *(u16x8*)(dst + 8) = o1;
}

// ---------------------------------------------------------------- FFN1 GEMM (r5 verbatim)
// h[p-P0] = relu(xb[plist[p]] . wt[e]^T + b1[e])
// 128x128 tile, BK=64, dbuf LDS, global_load_lds staging with source-side XOR
// swizzle, counted-vmcnt pipeline. XCD-chunked block swizzle.
__global__ __launch_bounds__(256) void moe_ffn1_kernel(
    const u16* __restrict__ xb, const u16* __restrict__ wt, const float* __restrict__ b1,
    const int* __restrict__ plist, const int* __restrict__ cnt, const int* __restrict__ off,
    u16* __restrict__ h, int P0, int P1)
{
    __shared__ __align__(16) u16 As[2][128 * 64];   // 2 x 16 KB
    __shared__ __align__(16) u16 Bs[2][128 * 64];   // 2 x 16 KB
    const int GX = 24, GY = 16;                     // grid = (24,16,8), nwg=3072
    int f = blockIdx.x + GX * (blockIdx.y + GY * blockIdx.z);
    int swz = (f & 7) * 384 + (f >> 3);             // bijective, chunk=384=one expert
    int nb = swz % GX;
    int t2 = swz / GX;
    int mb = t2 % GY;
    int e  = t2 / GY;

    int lo = off[e], hi = lo + cnt[e];
    if (lo < P0) lo = P0;
    if (hi > P1) hi = P1;
    const int Cl = hi - lo;
    if (Cl <= 0) return;
    const int n0 = nb * 128;
    const int tid = threadIdx.x;
    const int lane = tid & 63, wave = tid >> 6;
    const int wr = wave >> 1, wc = wave & 1;
    const int qq = lane >> 4, r = lane & 15;
    const int srow = tid >> 3;                      // 0..31 (row within 32-row round)
    const int gq = (tid & 7) ^ (srow & 7);          // swizzled source 16B-slot

    const u16* bsrc[4];
#pragma unroll
    for (int j = 0; j < 4; j++)
        bsrc[j] = wt + ((size_t)e * F_HID + n0 + j * 32 + srow) * D_EMB + gq * 8;

    for (int m0 = mb * 128; m0 < Cl; m0 += GY * 128) {
        const u16* asrc[4];
#pragma unroll
        for (int j = 0; j < 4; j++) {
            int mr = m0 + j * 32 + srow;
            if (mr > Cl - 1) mr = Cl - 1;
            asrc[j] = xb + (size_t)plist[lo + mr] * D_EMB + gq * 8;
        }
        f32x4 acc[4][4] = {};

        auto stage = [&](int kt, int buf) {
            const int k0 = kt * 64;
#pragma unroll
            for (int j = 0; j < 4; j++)
                gll16(asrc[j] + k0, &As[buf][j * 2048 + wave * 512]);
#pragma unroll
            for (int j = 0; j < 4; j++)
                gll16(bsrc[j] + k0, &Bs[buf][j * 2048 + wave * 512]);
        };
        auto compute = [&](int buf) {
#pragma unroll
            for (int kk = 0; kk < 2; kk++) {
                bfrag af[4], bf[4];
#pragma unroll
                for (int i = 0; i < 4; i++) {
                    int rowa = wr * 64 + i * 16 + r;
                    int rowb = wc * 64 + i * 16 + r;
                    int slot = ((qq + 4 * kk) ^ (r & 7)) * 8;
                    af[i] = *(const bfrag*)(&As[buf][rowa * 64 + slot]);
                    bf[i] = *(const bfrag*)(&Bs[buf][rowb * 64 + slot]);
                }
#pragma unroll
                for (int mi = 0; mi < 4; mi++)
#pragma unroll
                    for (int ni = 0; ni < 4; ni++)
                        acc[mi][ni] = mfma16(af[mi], bf[ni], acc[mi][ni]);
            }
        };

        waitv0();                        // drain prior epilogue stores (vmcnt-counted)
        stage(0, 0);
        for (int kt = 0; kt < 11; kt++) {
            stage(kt + 1, (kt + 1) & 1);
            waitv8(); sbar();            // tile kt landed everywhere; kt+1 in flight
            compute(kt & 1);
            sbar();                      // all reads of buf[kt&1] done
        }
        waitv0(); sbar();
        compute(1);                      // kt = 11

#pragma unroll
        for (int mi = 0; mi < 4; mi++)
#pragma unroll
            for (int ni = 0; ni < 4; ni++) {
                int col = n0 + wc * 64 + ni * 16 + r;
                float bias = b1[(size_t)e * F_HID + col];
#pragma unroll
                for (int i = 0; i < 4; i++) {
                    int m = m0 + wr * 64 + mi * 16 + qq * 4 + i;
                    if (m < Cl) {
                        float v = acc[mi][ni][i] + bias;
                        h[(size_t)(lo - P0 + m) * F_HID + col] = f2b(v > 0.f ? v : 0.f);
                    }
                }
            }
    }
}

// ---------------------------------------------------------------- FFN2 GEMM (r5 verbatim)
// y[p] = h[p-P0] . wt[e]^T + b2[e]  (plain stores, no atomics)
// 64x128 tile, BK=64, dbuf + counted-vmcnt pipeline, same swizzles as ffn1.
__global__ __launch_bounds__(256) void moe_ffn2_kernel(
    const u16* __restrict__ h, const u16* __restrict__ wt, const float* __restrict__ b2,
    const int* __restrict__ cnt, const int* __restrict__ off,
    float* __restrict__ y, int P0, int P1)
{
    __shared__ __align__(16) u16 As[2][64 * 64];    // 2 x 8 KB
    __shared__ __align__(16) u16 Bs[2][128 * 64];   // 2 x 16 KB
    const int GX = 6, GY = 32;                      // grid = (6,32,8), nwg=1536
    int f = blockIdx.x + GX * (blockIdx.y + GY * blockIdx.z);
    int swz = (f & 7) * 192 + (f >> 3);             // chunk=192=one expert
    int nb = swz % GX;
    int t2 = swz / GX;
    int mb = t2 % GY;
    int e  = t2 / GY;

    int lo = off[e], hi = lo + cnt[e];
    if (lo < P0) lo = P0;
    if (hi > P1) hi = P1;
    const int Cl = hi - lo;
    if (Cl <= 0) return;
    const int n0 = nb * 128;
    const int tid = threadIdx.x;
    const int lane = tid & 63, wave = tid >> 6;
    const int wr = wave >> 1, wc = wave & 1;
    const int qq = lane >> 4, r = lane & 15;
    const int srow = tid >> 3;
    const int gq = (tid & 7) ^ (srow & 7);
    const int hcap = P1 - P0;

    const u16* bsrc[4];
#pragma unroll
    for (int j = 0; j < 4; j++)
        bsrc[j] = wt + ((size_t)e * D_EMB + n0 + j * 32 + srow) * F_HID + gq * 8;

    for (int m0 = mb * 64; m0 < Cl; m0 += GY * 64) {
        const u16* asrc[2];
#pragma unroll
        for (int j = 0; j < 2; j++) {
            int mr = m0 + j * 32 + srow;
            if (mr > Cl - 1) mr = Cl - 1;
            asrc[j] = h + (size_t)(lo - P0 + ((mr < hcap) ? mr : hcap - 1)) * F_HID + gq * 8;
        }
        f32x4 acc[2][4] = {};

        auto stage = [&](int kt, int buf) {
            const int k0 = kt * 64;
#pragma unroll
            for (int j = 0; j < 2; j++)
                gll16(asrc[j] + k0, &As[buf][j * 2048 + wave * 512]);
#pragma unroll
            for (int j = 0; j < 4; j++)
                gll16(bsrc[j] + k0, &Bs[buf][j * 2048 + wave * 512]);
        };
        auto compute = [&](int buf) {
#pragma unroll
            for (int kk = 0; kk < 2; kk++) {
                bfrag af[2], bf[4];
#pragma unroll
                for (int i = 0; i < 2; i++) {
                    int rowa = wr * 32 + i * 16 + r;
                    int slot = ((qq + 4 * kk) ^ (r & 7)) * 8;
                    af[i] = *(const bfrag*)(&As[buf][rowa * 64 + slot]);
                }
#pragma unroll
                for (int i = 0; i < 4; i++) {
                    int rowb = wc * 64 + i * 16 + r;
                    int slot = ((qq + 4 * kk) ^ (r & 7)) * 8;
                    bf[i] = *(const bfrag*)(&Bs[buf][rowb * 64 + slot]);
                }
#pragma unroll
                for (int mi = 0; mi < 2; mi++)
#pragma unroll
                    for (int ni = 0; ni < 4; ni++)
                        acc[mi][ni] = mfma16(af[mi], bf[ni], acc[mi][ni]);
            }
        };

        waitv0();
        stage(0, 0);
        for (int kt = 0; kt < 47; kt++) {
            stage(kt + 1, (kt + 1) & 1);
            waitv6(); sbar();
            compute(kt & 1);
            sbar();
        }
        waitv0(); sbar();
        compute(1);                      // kt = 47

#pragma unroll
        for (int mi = 0; mi < 2; mi++)
#pragma unroll
            for (int ni = 0; ni < 4; ni++) {
                int col = n0 + wc * 64 + ni * 16 + r;
                float bias = b2[(size_t)e * D_EMB + col];
#pragma unroll
                for (int i = 0; i < 4; i++) {
                    int m = m0 + wr * 32 + mi * 16 + qq * 4 + i;
                    if (m < Cl)
                        y[(size_t)(lo + m) * D_EMB + col] = acc[mi][ni][i] + bias;
                }
            }
    }
}

// ---------------------------------------------------------------- combine
// out[t] = sum_k gate[t,k] * y[pos[t,k]]  (writes every token -> no zero pass)
__global__ __launch_bounds__(256) void moe_combine_kernel(
    const float* __restrict__ y, const int* __restrict__ tk_e,
    const float* __restrict__ tk_g, const int* __restrict__ pos,
    float4* __restrict__ out)
{
    int i = blockIdx.x * 256 + threadIdx.x;   // 786432 float4
    int t = i / 192;
    int c = i - t * 192;
    float4 a = make_float4(0.f, 0.f, 0.f, 0.f);
#pragma unroll
    for (int k = 0; k < 2; k++) {
        int e = tk_e[t * 2 + k];
        if (e >= 0) {
            float g = tk_g[t * 2 + k];
            float4 v = ((const float4*)(y + (size_t)pos[t * 2 + k] * D_EMB))[c];
            a.x += g * v.x; a.y += g * v.y; a.z += g * v.z; a.w += g * v.w;
        }
    }
    out[i] = a;
}

// ---------------------------------------------------------------- fallback fused FFN (fp32)
#define XSTR 776
#define HSTR 3080
#define BMF 8
__global__ __launch_bounds__(256) void moe_ffn_fused_f32(
    const float* __restrict__ x,
    const float* __restrict__ w1, const float* __restrict__ b1,
    const float* __restrict__ w2, const float* __restrict__ b2,
    const int* __restrict__ plist, const float* __restrict__ pg,
    const int* __restrict__ cnt, const int* __restrict__ off,
    float* __restrict__ out)
{
    __shared__ __align__(16) u16 xs[BMF * XSTR];
    __shared__ __align__(16) u16 hs[BMF * HSTR];
    const int e = blockIdx.x;
    const int Cl = cnt[e];
    if (Cl <= 0) return;
    const int O = off[e];
    const int tid = threadIdx.x;
    for (int t0 = blockIdx.y * BMF; t0 < Cl; t0 += gridDim.y * BMF) {
        for (int ci = tid; ci < BMF * 192; ci += 256) {
            int row = ci / 192, c = ci - row * 192;
            float4 v = make_float4(0.f, 0.f, 0.f, 0.f);
            if (t0 + row < Cl) {
                int tok = plist[O + t0 + row];
                v = *(const float4*)(x + (size_t)tok * D_EMB + c * 4);
            }
            u16* d = &xs[row * XSTR + c * 4];
            d[0] = f2b(v.x); d[1] = f2b(v.y); d[2] = f2b(v.z); d[3] = f2b(v.w);
        }
        __syncthreads();
        for (int wi = tid; wi < BMF * 768; wi += 256) {
            int row = wi / 768, nc = wi - row * 768;
            int n0 = nc * 4;
            float a0 = 0, a1 = 0, a2 = 0, a3 = 0;
            const float* wp = w1 + (size_t)e * D_EMB * F_HID + n0;
            const u16* xr = &xs[row * XSTR];
            for (int k = 0; k < D_EMB; k++) {
                float4 wv = *(const float4*)(wp + (size_t)k * F_HID);
                float xv = b2f(xr[k]);
                a0 += xv * wv.x; a1 += xv * wv.y; a2 += xv * wv.z; a3 += xv * wv.w;
            }
            const float* bp = b1 + (size_t)e * F_HID + n0;
            u16* hp = &hs[row * HSTR + n0];
            float v;
            v = a0 + bp[0]; hp[0] = f2b(v > 0.f ? v : 0.f);
            v = a1 + bp[1]; hp[1] = f2b(v > 0.f ? v : 0.f);
            v = a2 + bp[2]; hp[2] = f2b(v > 0.f ? v : 0.f);
            v = a3 + bp[3]; hp[3] = f2b(v > 0.f ? v : 0.f);
        }
        __syncthreads();
        for (int wi = tid; wi < BMF * 192; wi += 256) {
            int row = wi / 192, nc = wi - row * 192;
            int n0 = nc * 4;
            float a0 = 0, a1 = 0, a2 = 0, a3 = 0;
            const float* wp = w2 + (size_t)e * F_HID * D_EMB + n0;
            const u16* hr = &hs[row * HSTR];
            for (int k = 0; k < F_HID; k++) {
                float4 wv = *(const float4*)(wp + (size_t)k * D_EMB);
                float hv = b2f(hr[k]);
                a0 += hv * wv.x; a1 += hv * wv.y; a2 += hv * wv.z; a3 += hv * wv.w;
            }
            if (t0 + row < Cl) {
                int p = O + t0 + row;
                int tok = plist[p];
                float g = pg[p];
                const float* bp = b2 + (size_t)e * D_EMB + n0;
                float* op = out + (size_t)tok * D_EMB + n0;
                atomicAdd(&op[0], g * (a0 + bp[0]));
                atomicAdd(&op[1], g * (a1 + bp[1]));
                atomicAdd(&op[2], g * (a2 + bp[2]));
                atomicAdd(&op[3], g * (a3 + bp[3]));
            }
        }
        __syncthreads();
    }
}

// ---------------------------------------------------------------- launch
extern "C" void kernel_launch(void* const* d_in, const int* in_sizes, int n_in,
                              void* d_out, int out_size, void* d_ws, size_t ws_size,
                              hipStream_t stream) {
    const float* x     = (const float*)d_in[0];
    const float* noise = (const float*)d_in[1];
    const float* Wg    = (const float*)d_in[2];
    const float* bg    = (const float*)d_in[3];
    const float* Wn    = (const float*)d_in[4];
    const float* bn    = (const float*)d_in[5];
    const float* W1    = (const float*)d_in[6];
    const float* b1    = (const float*)d_in[7];
    const float* W2    = (const float*)d_in[8];
    const float* b2    = (const float*)d_in[9];
    float* out = (float*)d_out;

    // workspace layout (shared small region)
    char* ws = (char*)d_ws;
    int*   cnt    = (int*)(ws + 0);
    int*   off    = (int*)(ws + 256);
    int*   tk_e   = (int*)(ws + 1024);       // 32768 B
    float* tk_g   = (float*)(ws + 33792);    // 32768 B
    int*   plist  = (int*)(ws + 66560);      // 32768 B
    float* pg     = (float*)(ws + 99328);    // 32768 B
    int*   pos    = (int*)(ws + 132096);     // 32768 B
    const size_t SMALL  = 164864;
    const size_t WSZ    = 37748736ull;       // one transposed weight set (bf16)
    const size_t XB_SZ  = 6291456ull;        // 4096*768*2
    const size_t Y_SZ   = 25165824ull;       // 8192*768*4
    const size_t H_FULL = 50331648ull;       // 8192*3072*2

    // Plan A: single-pass, ONE shared weight buffer (transcvt W1 -> ffn1 ->
    // transcvt W2 -> ffn2). NEED_A = 119.7 MB (< known-good 126 MB floor).
    const size_t NEED_A = SMALL + WSZ + XB_SZ + Y_SZ + H_FULL;

    if (ws_size >= NEED_A) {
        u16*   wt = (u16*)(ws + SMALL);
        u16*   xb = (u16*)(ws + SMALL + WSZ);
        float* y  = (float*)(ws + SMALL + WSZ + XB_SZ);
        u16*   h  = (u16*)(ws + SMALL + WSZ + XB_SZ + Y_SZ);

        moe_router_v4<<<dim3(512), dim3(64), 0, stream>>>(
            x, noise, Wg, bg, Wn, bn, tk_e, tk_g, (ushort4*)xb);
        moe_plan_kernel<<<dim3(1), dim3(256), 0, stream>>>(
            tk_e, tk_g, cnt, off, plist, pg, pos);
        moe_transcvt_kernel<<<dim3(F_HID / 64, D_EMB / 64, 8), dim3(256), 0, stream>>>(
            W1, wt, D_EMB, F_HID);   // [e][768][3072] -> [e][3072][768]
        moe_ffn1_kernel<<<dim3(24, 16, 8), dim3(256), 0, stream>>>(
            xb, wt, b1, plist, cnt, off, h, 0, N_PAIR);
        moe_transcvt_kernel<<<dim3(D_EMB / 64, F_HID / 64, 8), dim3(256), 0, stream>>>(
            W2, wt, F_HID, D_EMB);   // [e][3072][768] -> [e][768][3072]
        moe_ffn2_kernel<<<dim3(6, 32, 8), dim3(256), 0, stream>>>(
            h, wt, b2, cnt, off, y, 0, N_PAIR);
        moe_combine_kernel<<<dim3(3072), dim3(256), 0, stream>>>(
            y, tk_e, tk_g, pos, (float4*)out);
        (void)in_sizes; (void)n_in; (void)out_size;
        return;
    }

    // Plan B: chunked, separate w1t/w2t buffers.
    const size_t B_BASE = SMALL + 2 * WSZ + XB_SZ + Y_SZ;
    int pchunk = 0;
    for (int p = N_PAIR; p >= 512; p >>= 1) {
        if (B_BASE + (size_t)p * F_HID * 2 <= ws_size) { pchunk = p; break; }
    }

    moe_router_v4<<<dim3(512), dim3(64), 0, stream>>>(
        x, noise, Wg, bg, Wn, bn, tk_e, tk_g,
        pchunk > 0 ? (ushort4*)(ws + SMALL + 2 * WSZ) : (ushort4*)0);
    moe_plan_kernel<<<dim3(1), dim3(256), 0, stream>>>(
        tk_e, tk_g, cnt, off, plist, pg, pos);

    if (pchunk > 0) {
        u16*   w1t = (u16*)(ws + SMALL);
        u16*   w2t = (u16*)(ws + SMALL + WSZ);
        u16*   xb  = (u16*)(ws + SMALL + 2 * WSZ);
        float* y   = (float*)(ws + SMALL + 2 * WSZ + XB_SZ);
        u16*   h   = (u16*)(ws + B_BASE);
        moe_transcvt_kernel<<<dim3(F_HID / 64, D_EMB / 64, 8), dim3(256), 0, stream>>>(
            W1, w1t, D_EMB, F_HID);
        moe_transcvt_kernel<<<dim3(D_EMB / 64, F_HID / 64, 8), dim3(256), 0, stream>>>(
            W2, w2t, F_HID, D_EMB);
        for (int c = 0; c < N_PAIR / pchunk; c++) {
            int P0 = c * pchunk, P1 = P0 + pchunk;
            moe_ffn1_kernel<<<dim3(24, 16, 8), dim3(256), 0, stream>>>(
                xb, w1t, b1, plist, cnt, off, h, P0, P1);
            moe_ffn2_kernel<<<dim3(6, 32, 8), dim3(256), 0, stream>>>(
                h, w2t, b2, cnt, off, y, P0, P1);
        }
        moe_combine_kernel<<<dim3(3072), dim3(256), 0, stream>>>(
            y, tk_e, tk_g, pos, (float4*)out);
    } else {
        moe_zero_kernel<<<dim3(3072), dim3(256), 0, stream>>>((uint4*)out);
        moe_ffn_fused_f32<<<dim3(8, 192), dim3(256), 0, stream>>>(
            x, W1, b1, W2, b2, plist, pg, cnt, off, out);
    }
    (void)in_sizes; (void)n_in; (void)out_size;
}